// Round 6
// baseline (3545.359 us; speedup 1.0000x reference)
//
#include <hip/hip_runtime.h>

typedef __bf16 bf16x8 __attribute__((ext_vector_type(8)));
typedef float f32x4 __attribute__((ext_vector_type(4)));
typedef unsigned int uint32;
typedef unsigned short u16;

#define T_STEPS 1024
#define CH_STR 784

// ---------------- LDS layout (byte offsets), 16B aligned ----------------
#define H0_OFF   0              // 2 ping-pong [16 rows][272B] (128 bf16 + 16B pad)
#define H1_OFF   8704
#define M1_OFF   17408          // [16][272B]
#define UCH_OFF  21760          // [32 s][16 r][48B] stride 784
#define YCH_OFF  46848
#define WL_OFF   71936          // 73 tiles x 1024B: [0..23]=Wih0, [24..28]=dC, [29..68]=mW1, [69..72]=mE
#define LDS_BYTES 146688

// ---------------- global frag buffer tiles (1 tile = 512 bf16 = 1KB) ----
#define TG0 0     // Wih0 [384,32]   KT=1 NT=24
#define TG1 24    // Whh0 [384,128]  KT=4 NT=24
#define TG2 120   // Wih1 [384,128]
#define TG3 216   // Whh1 [384,128]
#define TG4 312   // dC   [16,160]   KT=5 NT=1
#define TG5 317   // mW1  [128,160]  KT=5 NT=8
#define TG6 357   // mE   [16,128]   KT=4 NT=1
#define NT_TOT 361
#define SC_DC  369664
#define SC_ME  378880
#define SC_DBC 387072
#define SC_MBE 387136

static __device__ __forceinline__ u16 f2bf(float f) {
    uint32 u = __builtin_bit_cast(uint32, f);
    return (u16)((u + 0x7FFFu + ((u >> 16) & 1u)) >> 16);
}
static __device__ __forceinline__ float bf2f(u16 h) {
    uint32 u = ((uint32)h) << 16;
    return __builtin_bit_cast(float, u);
}
static __device__ __forceinline__ uint32 cvtpk(float a, float b) {
    uint32 r;
    asm("v_cvt_pk_bf16_f32 %0, %1, %2" : "=v"(r) : "v"(a), "v"(b));
    return r;
}
static __device__ __forceinline__ float sigm(float x) {
    return __builtin_amdgcn_rcpf(1.f + __builtin_amdgcn_exp2f(x * -1.4426950408889634f));
}
static __device__ __forceinline__ float tanh_fast(float x) {
    float xm = fmaxf(x, -30.f);
    float e = __builtin_amdgcn_exp2f(xm * -2.8853900817779268f);
    return fmaf(2.f, __builtin_amdgcn_rcpf(e + 1.f), -1.f);
}
static __device__ __forceinline__ f32x4 mfma16(bf16x8 a, bf16x8 b, f32x4 c) {
    return __builtin_amdgcn_mfma_f32_16x16x32_bf16(a, b, c, 0, 0, 0);
}
static __device__ __forceinline__ bf16x8 ldsAF(const char* p) {
    return __builtin_bit_cast(bf16x8, *(const uint4*)p);
}

// ---------------- prep1: combined matrices + biases (fp32), zero d_out ----------------
__global__ void prep1(const float* __restrict__ dW1, const float* __restrict__ db1,
                      const float* __restrict__ dW2, const float* __restrict__ db2,
                      const float* __restrict__ mW2, const float* __restrict__ mb2,
                      const float* __restrict__ mW3, const float* __restrict__ mb3,
                      char* __restrict__ ws, float* __restrict__ out) {
    int id = blockIdx.x * 256 + threadIdx.x;
    if (id == 0) *out = 0.f;
    if (id < 2304) {                       // dC[n][k] = sum_h dW2[n][h]*dW1[h][k]
        int n = id / 144, k = id % 144;
        float s = 0.f;
        for (int h = 0; h < 128; ++h) s += dW2[n * 128 + h] * dW1[h * 144 + k];
        ((float*)(ws + SC_DC))[id] = s;
    } else if (id < 4352) {                // mE[n][k] = sum_h mW3[n][h]*mW2[h][k]
        int e = id - 2304, n = e / 128, k = e % 128;
        float s = 0.f;
        for (int h = 0; h < 128; ++h) s += mW3[n * 128 + h] * mW2[h * 128 + k];
        ((float*)(ws + SC_ME))[e] = s;
    } else if (id < 4368) {                // dbC = dW2@db1 + db2
        int n = id - 4352;
        float s = db2[n];
        for (int h = 0; h < 128; ++h) s += dW2[n * 128 + h] * db1[h];
        ((float*)(ws + SC_DBC))[n] = s;
    } else if (id < 4384) {                // mbE = mW3@mb2 + mb3
        int n = id - 4368;
        float s = mb3[n];
        for (int h = 0; h < 128; ++h) s += mW3[n * 128 + h] * mb2[h];
        ((float*)(ws + SC_MBE))[n] = s;
    }
}

// ---------------- prep2: pack weights into MFMA B-fragment order (bf16) ----------------
__global__ void prep2(const float* __restrict__ W0, const float* __restrict__ W1,
                      const float* __restrict__ W2, const float* __restrict__ W3,
                      const float* __restrict__ W5, char* __restrict__ ws) {
    const int tt = blockIdx.x;     // 0..360
    const int lane = threadIdx.x;  // 0..63
    const int cum[8] = {TG0, TG1, TG2, TG3, TG4, TG5, TG6, NT_TOT};
    const int Kreal[7] = {32, 128, 128, 128, 144, 144, 128};
    const int KT[7] = {1, 4, 4, 4, 5, 5, 4};
    const float* Ws[7] = {W0, W1, W2, W3, (const float*)(ws + SC_DC), W5, (const float*)(ws + SC_ME)};
    int g = 0;
    while (tt >= cum[g + 1]) ++g;
    const int tl = tt - cum[g];
    const int kt = tl % KT[g];
    const int n = (tl / KT[g]) * 16 + (lane & 15);
    const float* W = Ws[g];
    u16* o = (u16*)ws + tt * 512 + lane * 8;
#pragma unroll
    for (int j = 0; j < 8; ++j) {
        int k = kt * 32 + (lane >> 4) * 8 + j;
        o[j] = (k < Kreal[g]) ? f2bf(W[n * Kreal[g] + k]) : (u16)0;
    }
}

// ---------------- main: 16 WG x 512 thr (8 waves, 2 waves/SIMD, 256-reg budget) ----------
__global__ __launch_bounds__(512, 2) void rnn_main(
    const float* __restrict__ u, const float* __restrict__ yg, const float* __restrict__ h0g,
    const char* __restrict__ ws, const float* __restrict__ mb1g,
    const float* __restrict__ dbCg, const float* __restrict__ mbEg,
    float* __restrict__ out) {
    __shared__ __align__(16) char smem[LDS_BYTES];
    const int tid = threadIdx.x;
    const int lane = tid & 63;
    const int w = tid >> 6;       // wave 0..7: owns cols [w*16, w*16+16)
    const int lr = lane & 15;
    const int lg = lane >> 4;
    const int r0 = blockIdx.x * 16;
    const uint4* F4 = (const uint4*)ws;
    const f32x4 zero = {0.f, 0.f, 0.f, 0.f};

    // ---- init: load h0 -> LDS bf16 (buffer 0), copy LDS-resident weights ----
    for (int i = tid; i < 1024; i += 512) {  // 2 layers x 16 rows x 32 float4
        int lay = i >> 9, rem = i & 511, rr = rem >> 5, k4 = rem & 31;
        float4 v = *(const float4*)(h0g + (lay * 256 + r0 + rr) * 128 + k4 * 4);
        uint2 pk;
        pk.x = (uint32)f2bf(v.x) | ((uint32)f2bf(v.y) << 16);
        pk.y = (uint32)f2bf(v.z) | ((uint32)f2bf(v.w) << 16);
        *(uint2*)(smem + H0_OFF + lay * 8704 + rr * 272 + k4 * 8) = pk;
    }
    for (int i = tid; i < 73 * 64; i += 512) {  // Wih0,dC,mW1,mE -> WL
        int li = i >> 6, ln2 = i & 63;
        int gt2 = (li < 24) ? li : (li < 29) ? TG4 + (li - 24) : (li < 69) ? TG5 + (li - 29) : TG6 + (li - 69);
        *((uint4*)(smem + WL_OFF) + i) = F4[gt2 * 64 + ln2];
    }
    __syncthreads();

    // ---- per-wave register weights (Whh0/Wih1/Whh1), staged THROUGH LDS so the
    //      compiler cannot rematerialize the loads inside the t-loop ----
    bf16x8 wW[3][3][4];  // [mat][gate][kt], mat 0=Whh0 1=Wih1 2=Whh1
    for (int p = 0; p < 6; ++p) {
        for (int i = tid; i < 3072; i += 512)
            *((uint4*)(smem + UCH_OFF) + i) = F4[(TG1 + p * 48) * 64 + i];
        __syncthreads();
#pragma unroll
        for (int mat = 0; mat < 3; ++mat)
#pragma unroll
            for (int gg = 0; gg < 3; ++gg) {
                int rel0 = mat * 96 + gg * 32 + w * 4;
                if (rel0 >= p * 48 && rel0 < p * 48 + 48) {
#pragma unroll
                    for (int kt = 0; kt < 4; ++kt)
                        wW[mat][gg][kt] = ldsAF(smem + UCH_OFF + (rel0 - p * 48 + kt) * 1024 + lane * 16);
                }
            }
        __syncthreads();
    }
    // dC register-resident (critical x-path): read from WL (stable across loop)
    bf16x8 wdr[5];
#pragma unroll
    for (int k = 0; k < 5; ++k) wdr[k] = ldsAF(smem + WL_OFF + (24 + k) * 1024 + lane * 16);

    // ---- per-lane constants & register-resident hold state ----
    const float mb1_c = mb1g[w * 16 + lr];
    const float mbE_l = mbEg[lr];
    float dbc4[4];
#pragma unroll
    for (int i = 0; i < 4; ++i) dbc4[i] = dbCg[lg * 4 + i];
    float hp0[4], hp1[4];
#pragma unroll
    for (int i = 0; i < 4; ++i) {
        hp0[i] = h0g[(r0 + lg * 4 + i) * 128 + w * 16 + lr];
        hp1[i] = h0g[(256 + r0 + lg * 4 + i) * 128 + w * 16 + lr];
    }
    float loss = 0.f;
    const int c2 = (w * 16 + lr) * 2;
    const int bp0 = (lr + (lg & 1) * 32) * 4;  // bpermute byte-addr of x source lane

    // initial GRU0 h-fragments (h0 buffer 0, t=0)
    bf16x8 pf_ah[4];
#pragma unroll
    for (int kt = 0; kt < 4; ++kt) pf_ah[kt] = ldsAF(smem + H0_OFF + lr * 272 + kt * 64 + lg * 16);

#pragma unroll 2
    for (int t = 0; t < T_STEPS; ++t) {
        const char* h0c = smem + H0_OFF + (t & 1) * 4352;
        char* h0n = smem + H0_OFF + ((t & 1) ^ 1) * 4352;
        const char* h1c = smem + H1_OFF + (t & 1) * 4352;
        char* h1n = smem + H1_OFF + ((t & 1) ^ 1) * 4352;
        const int s = t & 31, sp = (t - 1) & 31;
        const char* h1r = h1c + lr * 272;

        // ---- issue x-input reads (old chunk slot sp + h1c; dC already in regs) ----
        bf16x8 ad0 = ldsAF((lg < 2) ? (smem + UCH_OFF + sp * CH_STR + lr * 48 + lg * 16)
                                    : (h1r + (lg - 2) * 16));
        bf16x8 ad1 = ldsAF(h1r + 32 + lg * 16);
        bf16x8 ad2 = ldsAF(h1r + 96 + lg * 16);
        bf16x8 ad3 = ldsAF(h1r + 160 + lg * 16);
        bf16x8 ad4 = ldsAF(h1r + 224 + (lg & 1) * 16);  // lg>=2: K-pad cols, B is zero there

        // ---- GRU0 h-part: 12 register-only MFMAs (hide the ds_read latency) ----
        f32x4 rA = mfma16(pf_ah[0], wW[0][0][0], zero);
        rA = mfma16(pf_ah[1], wW[0][0][1], rA);
        f32x4 rB = mfma16(pf_ah[2], wW[0][0][2], zero);
        rB = mfma16(pf_ah[3], wW[0][0][3], rB);
        f32x4 zA = mfma16(pf_ah[0], wW[0][1][0], zero);
        zA = mfma16(pf_ah[1], wW[0][1][1], zA);
        f32x4 zB = mfma16(pf_ah[2], wW[0][1][2], zero);
        zB = mfma16(pf_ah[3], wW[0][1][3], zB);
        f32x4 nA = mfma16(pf_ah[0], wW[0][2][0], zero);
        nA = mfma16(pf_ah[1], wW[0][2][1], nA);
        f32x4 nB = mfma16(pf_ah[2], wW[0][2][2], zero);
        nB = mfma16(pf_ah[3], wW[0][2][3], nB);

        // ---- x(t-1) = [u(t-1)|h1(t-1)] @ dC^T + dbC (redundant per wave, in-register) ----
        f32x4 xa = mfma16(wdr[0], ad0, zero);
        xa = mfma16(wdr[1], ad1, xa);
        xa = mfma16(wdr[2], ad2, xa);
        f32x4 xb = mfma16(wdr[3], ad3, zero);
        xb = mfma16(wdr[4], ad4, xb);
        uint32 pk0 = cvtpk(xa[0] + xb[0] + dbc4[0], xa[1] + xb[1] + dbc4[1]);
        uint32 pk1 = cvtpk(xa[2] + xb[2] + dbc4[2], xa[3] + xb[3] + dbc4[3]);
        if (t == 0) { pk0 = 0u; pk1 = 0u; }
        uint32 d0 = (uint32)__builtin_amdgcn_ds_bpermute(bp0, (int)pk0);
        uint32 d1 = (uint32)__builtin_amdgcn_ds_bpermute(bp0, (int)pk1);
        uint32 d2 = (uint32)__builtin_amdgcn_ds_bpermute(bp0 + 64, (int)pk0);
        uint32 d3 = (uint32)__builtin_amdgcn_ds_bpermute(bp0 + 64, (int)pk1);
        bf16x8 xfrag = __builtin_bit_cast(bf16x8, (uint4){d0, d1, d2, d3});

        // ---- chunk refill every 32 steps (paired-channel u32 stores) ----
        if ((t & 31) == 0) {
            __syncthreads();
#pragma unroll
            for (int it = 0; it < 8; ++it) {
                int g = it * 16 + (tid >> 5);     // 0..127 = (rr2, chp)
                int rr2 = g >> 3, chp = g & 7, ss = lane & 31;
                const float* up = u + (r0 + rr2) * 16384 + (2 * chp) * 1024 + t + ss;
                *(uint32*)(smem + UCH_OFF + ss * CH_STR + rr2 * 48 + chp * 4) =
                    cvtpk(up[0], up[1024]);
                int gt = t - 1 + ss;
                const float* yp = yg + (r0 + rr2) * 16384 + (2 * chp) * 1024 + gt;
                uint32 py = (gt >= 0) ? cvtpk(yp[0], yp[1024]) : 0u;
                *(uint32*)(smem + YCH_OFF + ss * CH_STR + rr2 * 48 + chp * 4) = py;
            }
            __syncthreads();
        }

        // ---- GRU0 input-part + m1(t-1) ----
        bf16x8 ufrag = ldsAF(smem + UCH_OFF + s * CH_STR + lr * 48 + (lg & 1) * 16);
        bf16x8 a_inp = (lg < 2) ? ufrag : xfrag;
        bf16x8 b0r = ldsAF(smem + WL_OFF + (0 * 8 + w) * 1024 + lane * 16);
        bf16x8 b0z = ldsAF(smem + WL_OFF + (1 * 8 + w) * 1024 + lane * 16);
        bf16x8 b0n = ldsAF(smem + WL_OFF + (2 * 8 + w) * 1024 + lane * 16);
        rA = mfma16(a_inp, b0r, rA);
        zA = mfma16(a_inp, b0z, zA);
        f32x4 nI = mfma16(a_inp, b0n, zero);
        const char* h0r = h0c + lr * 272;
        bf16x8 am0 = (lg < 2) ? xfrag : ldsAF(h0r + (lg - 2) * 16);
        bf16x8 am1 = ldsAF(h0r + 32 + lg * 16);
        bf16x8 am2 = ldsAF(h0r + 96 + lg * 16);
        bf16x8 am3 = ldsAF(h0r + 160 + lg * 16);
        bf16x8 am4 = ldsAF(h0r + 224 + (lg & 1) * 16);  // K-pad cols: B zero
        const int mb = 29 + w * 5;
        f32x4 mA = mfma16(am1, ldsAF(smem + WL_OFF + (mb + 1) * 1024 + lane * 16), zero);
        mA = mfma16(am2, ldsAF(smem + WL_OFF + (mb + 2) * 1024 + lane * 16), mA);
        mA = mfma16(am0, ldsAF(smem + WL_OFF + (mb + 0) * 1024 + lane * 16), mA);
        f32x4 mB = mfma16(am3, ldsAF(smem + WL_OFF + (mb + 3) * 1024 + lane * 16), zero);
        mB = mfma16(am4, ldsAF(smem + WL_OFF + (mb + 4) * 1024 + lane * 16), mB);
#pragma unroll
        for (int i = 0; i < 4; ++i) {
            float rr = sigm(rA[i] + rB[i]);
            float zz = sigm(zA[i] + zB[i]);
            float nn = tanh_fast(fmaf(rr, nA[i] + nB[i], nI[i]));
            float hnew = fmaf(zz, hp0[i] - nn, nn);
            hp0[i] = hnew;
            *(u16*)(h0n + (lg * 4 + i) * 272 + c2) = (u16)cvtpk(hnew, hnew);
            float mv = fmaxf(mA[i] + mB[i] + mb1_c, 0.f);
            *(u16*)(smem + M1_OFF + (lg * 4 + i) * 272 + c2) = (u16)cvtpk(mv, mv);
        }
        // prefetch h1c fragments for phase 2 (buffer stable this step)
        bf16x8 pf_av[4];
#pragma unroll
        for (int kt = 0; kt < 4; ++kt) pf_av[kt] = ldsAF(h1r + kt * 64 + lg * 16);
        __syncthreads();

        // ================= PHASE 2: GRU1(t) + loss(t-1) =================
        const char* h0nr = h0n + lr * 272;
        bf16x8 ag[4];
#pragma unroll
        for (int kt = 0; kt < 4; ++kt) ag[kt] = ldsAF(h0nr + kt * 64 + lg * 16);
        bf16x8 q0, q1, q2, q3, we0, we1, we2, we3;
        if (w == 7) {
            const char* m1r = smem + M1_OFF + lr * 272;
            q0 = ldsAF(m1r + lg * 16);
            q1 = ldsAF(m1r + 64 + lg * 16);
            q2 = ldsAF(m1r + 128 + lg * 16);
            q3 = ldsAF(m1r + 192 + lg * 16);
            we0 = ldsAF(smem + WL_OFF + 69 * 1024 + lane * 16);
            we1 = ldsAF(smem + WL_OFF + 70 * 1024 + lane * 16);
            we2 = ldsAF(smem + WL_OFF + 71 * 1024 + lane * 16);
            we3 = ldsAF(smem + WL_OFF + 72 * 1024 + lane * 16);
        }
        // av-based chains first (prefetched operands, register-only)
        f32x4 bRh = mfma16(pf_av[0], wW[2][0][0], zero);
        bRh = mfma16(pf_av[1], wW[2][0][1], bRh);
        bRh = mfma16(pf_av[2], wW[2][0][2], bRh);
        bRh = mfma16(pf_av[3], wW[2][0][3], bRh);
        f32x4 bZh = mfma16(pf_av[0], wW[2][1][0], zero);
        bZh = mfma16(pf_av[1], wW[2][1][1], bZh);
        bZh = mfma16(pf_av[2], wW[2][1][2], bZh);
        bZh = mfma16(pf_av[3], wW[2][1][3], bZh);
        f32x4 bNh = mfma16(pf_av[0], wW[2][2][0], zero);
        bNh = mfma16(pf_av[1], wW[2][2][1], bNh);
        bNh = mfma16(pf_av[2], wW[2][2][2], bNh);
        bNh = mfma16(pf_av[3], wW[2][2][3], bNh);
        f32x4 bRi = mfma16(ag[0], wW[1][0][0], zero);
        bRi = mfma16(ag[1], wW[1][0][1], bRi);
        bRi = mfma16(ag[2], wW[1][0][2], bRi);
        bRi = mfma16(ag[3], wW[1][0][3], bRi);
        f32x4 bZi = mfma16(ag[0], wW[1][1][0], zero);
        bZi = mfma16(ag[1], wW[1][1][1], bZi);
        bZi = mfma16(ag[2], wW[1][1][2], bZi);
        bZi = mfma16(ag[3], wW[1][1][3], bZi);
        f32x4 bNi = mfma16(ag[0], wW[1][2][0], zero);
        bNi = mfma16(ag[1], wW[1][2][1], bNi);
        bNi = mfma16(ag[2], wW[1][2][2], bNi);
        bNi = mfma16(ag[3], wW[1][2][3], bNi);
        if (w == 7) {  // y_hat(t-1) = m1(t-1) @ mE^T + mbE ; loss
            f32x4 lA = mfma16(q0, we0, zero);
            lA = mfma16(q1, we1, lA);
            f32x4 lB = mfma16(q2, we2, zero);
            lB = mfma16(q3, we3, lB);
            const float gd = (t > 0) ? 1.f : 0.f;
#pragma unroll
            for (int i = 0; i < 4; ++i) {
                float yh = lA[i] + lB[i] + mbE_l;
                float yv = bf2f(*(const u16*)(smem + YCH_OFF + s * CH_STR + (lg * 4 + i) * 48 + lr * 2));
                float d = yh - yv;
                loss = fmaf(gd * d, d, loss);
            }
        }
#pragma unroll
        for (int i = 0; i < 4; ++i) {
            float rr = sigm(bRi[i] + bRh[i]);
            float zz = sigm(bZi[i] + bZh[i]);
            float nn = tanh_fast(fmaf(rr, bNh[i], bNi[i]));
            float hnew = fmaf(zz, hp1[i] - nn, nn);
            hp1[i] = hnew;
            *(u16*)(h1n + (lg * 4 + i) * 272 + c2) = (u16)cvtpk(hnew, hnew);
        }
        // ag(t) fragments ARE next step's GRU0 h-fragments (same addresses) — free prefetch
#pragma unroll
        for (int kt = 0; kt < 4; ++kt) pf_ah[kt] = ag[kt];
        __syncthreads();
    }

    // ================= tail: m1(1023) + loss(1023) =================
    {
        const char* h0c = smem + H0_OFF;   // buffer 0 = h0n(1023)
        const char* h1c = smem + H1_OFF;   // buffer 0 = h1n(1023)
        const char* h1r = h1c + lr * 272;
        const char* h0r = h0c + lr * 272;
        bf16x8 ad0 = ldsAF((lg < 2) ? (smem + UCH_OFF + 31 * CH_STR + lr * 48 + lg * 16)
                                    : (h1r + (lg - 2) * 16));
        bf16x8 ad1 = ldsAF(h1r + 32 + lg * 16);
        bf16x8 ad2 = ldsAF(h1r + 96 + lg * 16);
        bf16x8 ad3 = ldsAF(h1r + 160 + lg * 16);
        bf16x8 ad4 = ldsAF(h1r + 224 + (lg & 1) * 16);
        f32x4 xa = mfma16(wdr[0], ad0, zero);
        xa = mfma16(wdr[1], ad1, xa);
        xa = mfma16(wdr[2], ad2, xa);
        f32x4 xb = mfma16(wdr[3], ad3, zero);
        xb = mfma16(wdr[4], ad4, xb);
        uint32 pk0 = cvtpk(xa[0] + xb[0] + dbc4[0], xa[1] + xb[1] + dbc4[1]);
        uint32 pk1 = cvtpk(xa[2] + xb[2] + dbc4[2], xa[3] + xb[3] + dbc4[3]);
        uint32 d0 = (uint32)__builtin_amdgcn_ds_bpermute(bp0, (int)pk0);
        uint32 d1 = (uint32)__builtin_amdgcn_ds_bpermute(bp0, (int)pk1);
        uint32 d2 = (uint32)__builtin_amdgcn_ds_bpermute(bp0 + 64, (int)pk0);
        uint32 d3 = (uint32)__builtin_amdgcn_ds_bpermute(bp0 + 64, (int)pk1);
        bf16x8 xfrag = __builtin_bit_cast(bf16x8, (uint4){d0, d1, d2, d3});
        bf16x8 am0 = (lg < 2) ? xfrag : ldsAF(h0r + (lg - 2) * 16);
        bf16x8 am1 = ldsAF(h0r + 32 + lg * 16);
        bf16x8 am2 = ldsAF(h0r + 96 + lg * 16);
        bf16x8 am3 = ldsAF(h0r + 160 + lg * 16);
        bf16x8 am4 = ldsAF(h0r + 224 + (lg & 1) * 16);
        const int mb = 29 + w * 5;
        f32x4 m = mfma16(am0, ldsAF(smem + WL_OFF + (mb + 0) * 1024 + lane * 16), zero);
        m = mfma16(am1, ldsAF(smem + WL_OFF + (mb + 1) * 1024 + lane * 16), m);
        m = mfma16(am2, ldsAF(smem + WL_OFF + (mb + 2) * 1024 + lane * 16), m);
        m = mfma16(am3, ldsAF(smem + WL_OFF + (mb + 3) * 1024 + lane * 16), m);
        m = mfma16(am4, ldsAF(smem + WL_OFF + (mb + 4) * 1024 + lane * 16), m);
#pragma unroll
        for (int i = 0; i < 4; ++i) {
            float mv = fmaxf(m[i] + mb1_c, 0.f);
            *(u16*)(smem + M1_OFF + (lg * 4 + i) * 272 + c2) = (u16)cvtpk(mv, mv);
        }
        __syncthreads();
        if (w == 7) {
            const char* m1r = smem + M1_OFF + lr * 272;
            bf16x8 q0 = ldsAF(m1r + lg * 16);
            bf16x8 q1 = ldsAF(m1r + 64 + lg * 16);
            bf16x8 q2 = ldsAF(m1r + 128 + lg * 16);
            bf16x8 q3 = ldsAF(m1r + 192 + lg * 16);
            f32x4 lA = mfma16(q0, ldsAF(smem + WL_OFF + 69 * 1024 + lane * 16), zero);
            lA = mfma16(q1, ldsAF(smem + WL_OFF + 70 * 1024 + lane * 16), lA);
            f32x4 lB = mfma16(q2, ldsAF(smem + WL_OFF + 71 * 1024 + lane * 16), zero);
            lB = mfma16(q3, ldsAF(smem + WL_OFF + 72 * 1024 + lane * 16), lB);
#pragma unroll
            for (int i = 0; i < 4; ++i) {
                float yh = lA[i] + lB[i] + mbE_l;
                float yv = yg[(r0 + lg * 4 + i) * 16384 + lr * 1024 + 1023];
                float d = yh - yv;
                loss = fmaf(d, d, loss);
            }
        }
    }

    if (w == 7) {
#pragma unroll
        for (int off = 32; off > 0; off >>= 1) loss += __shfl_down(loss, off, 64);
        if (lane == 0) atomicAdd(out, loss);
    }
}

extern "C" void kernel_launch(void* const* d_in, const int* in_sizes, int n_in,
                              void* d_out, int out_size, void* d_ws, size_t ws_size,
                              hipStream_t stream) {
    const float* u    = (const float*)d_in[0];
    const float* y    = (const float*)d_in[1];
    const float* h0   = (const float*)d_in[2];
    const float* Wih0 = (const float*)d_in[3];
    const float* Whh0 = (const float*)d_in[4];
    const float* Wih1 = (const float*)d_in[5];
    const float* Whh1 = (const float*)d_in[6];
    const float* dW1  = (const float*)d_in[7];
    const float* db1  = (const float*)d_in[8];
    const float* dW2  = (const float*)d_in[9];
    const float* db2  = (const float*)d_in[10];
    const float* mW1  = (const float*)d_in[11];
    const float* mb1  = (const float*)d_in[12];
    const float* mW2  = (const float*)d_in[13];
    const float* mb2  = (const float*)d_in[14];
    const float* mW3  = (const float*)d_in[15];
    const float* mb3  = (const float*)d_in[16];
    float* out = (float*)d_out;
    char* ws = (char*)d_ws;

    prep1<<<dim3(18), dim3(256), 0, stream>>>(dW1, db1, dW2, db2, mW2, mb2, mW3, mb3, ws, out);
    prep2<<<dim3(NT_TOT), dim3(64), 0, stream>>>(Wih0, Whh0, Wih1, Whh1, mW1, ws);
    rnn_main<<<dim3(16), dim3(512), 0, stream>>>(u, y, h0, ws, mb1,
                                                 (const float*)(ws + SC_DBC),
                                                 (const float*)(ws + SC_MBE), out);
}

// Round 7
// 3052.880 us; speedup vs baseline: 1.1613x; 1.1613x over previous
//
#include <hip/hip_runtime.h>

typedef __bf16 bf16x8 __attribute__((ext_vector_type(8)));
typedef float f32x4 __attribute__((ext_vector_type(4)));
typedef unsigned int uint32;
typedef unsigned short u16;

#define T_STEPS 1024
#define CH_STR 784

// ---------------- LDS layout (byte offsets), 16B aligned ----------------
#define H0_OFF   0              // 2 ping-pong [16 rows][272B] (128 bf16 + 16B pad)
#define H1_OFF   8704
#define M1_OFF   17408          // [16][272B]
#define UCH_OFF  21760          // [32 s][16 r][48B] stride 784 (4-way, not 32-way conflicts)
#define YCH_OFF  46848
#define WL_OFF   71936          // 73 tiles x 1024B: [0..23]=Wih0, [24..28]=dC, [29..68]=mW1, [69..72]=mE
#define LDS_BYTES 146688

// ---------------- global frag buffer tiles (1 tile = 512 bf16 = 1KB) ----
#define TG0 0     // Wih0 [384,32]   KT=1 NT=24
#define TG1 24    // Whh0 [384,128]  KT=4 NT=24
#define TG2 120   // Wih1 [384,128]
#define TG3 216   // Whh1 [384,128]
#define TG4 312   // dC   [16,160]   KT=5 NT=1
#define TG5 317   // mW1  [128,160]  KT=5 NT=8
#define TG6 357   // mE   [16,128]   KT=4 NT=1
#define NT_TOT 361
#define SC_DC  369664
#define SC_ME  378880
#define SC_DBC 387072
#define SC_MBE 387136

static __device__ __forceinline__ u16 f2bf(float f) {
    uint32 u = __builtin_bit_cast(uint32, f);
    return (u16)((u + 0x7FFFu + ((u >> 16) & 1u)) >> 16);
}
static __device__ __forceinline__ float bf2f(u16 h) {
    uint32 u = ((uint32)h) << 16;
    return __builtin_bit_cast(float, u);
}
static __device__ __forceinline__ uint32 cvtpk(float a, float b) {
    uint32 r;
    asm("v_cvt_pk_bf16_f32 %0, %1, %2" : "=v"(r) : "v"(a), "v"(b));
    return r;
}
static __device__ __forceinline__ float sigm(float x) {
    return __builtin_amdgcn_rcpf(1.f + __builtin_amdgcn_exp2f(x * -1.4426950408889634f));
}
static __device__ __forceinline__ float tanh_fast(float x) {
    float xm = fmaxf(x, -30.f);
    float e = __builtin_amdgcn_exp2f(xm * -2.8853900817779268f);
    return fmaf(2.f, __builtin_amdgcn_rcpf(e + 1.f), -1.f);
}
static __device__ __forceinline__ f32x4 mfma16(bf16x8 a, bf16x8 b, f32x4 c) {
    return __builtin_amdgcn_mfma_f32_16x16x32_bf16(a, b, c, 0, 0, 0);
}
static __device__ __forceinline__ bf16x8 ldsAF(const char* p) {
    return __builtin_bit_cast(bf16x8, *(const uint4*)p);
}

// ---------------- prep1: combined matrices + biases (fp32), zero d_out ----------------
__global__ void prep1(const float* __restrict__ dW1, const float* __restrict__ db1,
                      const float* __restrict__ dW2, const float* __restrict__ db2,
                      const float* __restrict__ mW2, const float* __restrict__ mb2,
                      const float* __restrict__ mW3, const float* __restrict__ mb3,
                      char* __restrict__ ws, float* __restrict__ out) {
    int id = blockIdx.x * 256 + threadIdx.x;
    if (id == 0) *out = 0.f;
    if (id < 2304) {                       // dC[n][k] = sum_h dW2[n][h]*dW1[h][k]
        int n = id / 144, k = id % 144;
        float s = 0.f;
        for (int h = 0; h < 128; ++h) s += dW2[n * 128 + h] * dW1[h * 144 + k];
        ((float*)(ws + SC_DC))[id] = s;
    } else if (id < 4352) {                // mE[n][k] = sum_h mW3[n][h]*mW2[h][k]
        int e = id - 2304, n = e / 128, k = e % 128;
        float s = 0.f;
        for (int h = 0; h < 128; ++h) s += mW3[n * 128 + h] * mW2[h * 128 + k];
        ((float*)(ws + SC_ME))[e] = s;
    } else if (id < 4368) {                // dbC = dW2@db1 + db2
        int n = id - 4352;
        float s = db2[n];
        for (int h = 0; h < 128; ++h) s += dW2[n * 128 + h] * db1[h];
        ((float*)(ws + SC_DBC))[n] = s;
    } else if (id < 4384) {                // mbE = mW3@mb2 + mb3
        int n = id - 4368;
        float s = mb3[n];
        for (int h = 0; h < 128; ++h) s += mW3[n * 128 + h] * mb2[h];
        ((float*)(ws + SC_MBE))[n] = s;
    }
}

// ---------------- prep2: pack weights into MFMA B-fragment order (bf16) ----------------
__global__ void prep2(const float* __restrict__ W0, const float* __restrict__ W1,
                      const float* __restrict__ W2, const float* __restrict__ W3,
                      const float* __restrict__ W5, char* __restrict__ ws) {
    const int tt = blockIdx.x;     // 0..360
    const int lane = threadIdx.x;  // 0..63
    const int cum[8] = {TG0, TG1, TG2, TG3, TG4, TG5, TG6, NT_TOT};
    const int Kreal[7] = {32, 128, 128, 128, 144, 144, 128};
    const int KT[7] = {1, 4, 4, 4, 5, 5, 4};
    const float* Ws[7] = {W0, W1, W2, W3, (const float*)(ws + SC_DC), W5, (const float*)(ws + SC_ME)};
    int g = 0;
    while (tt >= cum[g + 1]) ++g;
    const int tl = tt - cum[g];
    const int kt = tl % KT[g];
    const int n = (tl / KT[g]) * 16 + (lane & 15);
    const float* W = Ws[g];
    u16* o = (u16*)ws + tt * 512 + lane * 8;
#pragma unroll
    for (int j = 0; j < 8; ++j) {
        int k = kt * 32 + (lane >> 4) * 8 + j;
        o[j] = (k < Kreal[g]) ? f2bf(W[n * Kreal[g] + k]) : (u16)0;
    }
}

// ---------------- main: 16 WG x 512 thr (8 waves, 2 waves/SIMD, 256-reg budget) ----------
__global__ __launch_bounds__(512, 2) void rnn_main(
    const float* __restrict__ u, const float* __restrict__ yg, const float* __restrict__ h0g,
    const char* __restrict__ ws, const float* __restrict__ mb1g,
    const float* __restrict__ dbCg, const float* __restrict__ mbEg,
    float* __restrict__ out) {
    __shared__ __align__(16) char smem[LDS_BYTES];
    const int tid = threadIdx.x;
    const int lane = tid & 63;
    const int w = tid >> 6;       // wave 0..7: owns cols [w*16, w*16+16)
    const int lr = lane & 15;
    const int lg = lane >> 4;
    const int r0 = blockIdx.x * 16;
    const uint4* F4 = (const uint4*)ws;
    const f32x4 zero = {0.f, 0.f, 0.f, 0.f};

    // ---- init: load h0 -> LDS bf16 (buffer 0), copy LDS-resident weights ----
    for (int i = tid; i < 1024; i += 512) {  // 2 layers x 16 rows x 32 float4
        int lay = i >> 9, rem = i & 511, rr = rem >> 5, k4 = rem & 31;
        float4 v = *(const float4*)(h0g + (lay * 256 + r0 + rr) * 128 + k4 * 4);
        uint2 pk;
        pk.x = (uint32)f2bf(v.x) | ((uint32)f2bf(v.y) << 16);
        pk.y = (uint32)f2bf(v.z) | ((uint32)f2bf(v.w) << 16);
        *(uint2*)(smem + H0_OFF + lay * 8704 + rr * 272 + k4 * 8) = pk;
    }
    for (int i = tid; i < 73 * 64; i += 512) {  // Wih0,dC,mW1,mE -> WL
        int li = i >> 6, ln2 = i & 63;
        int gt2 = (li < 24) ? li : (li < 29) ? TG4 + (li - 24) : (li < 69) ? TG5 + (li - 29) : TG6 + (li - 69);
        *((uint4*)(smem + WL_OFF) + i) = F4[gt2 * 64 + ln2];
    }
    __syncthreads();

    // ---- per-wave register weights (Whh0/Wih1/Whh1), staged THROUGH LDS so the
    //      compiler cannot rematerialize the loads inside the t-loop ----
    bf16x8 wW[3][3][4];  // [mat][gate][kt], mat 0=Whh0 1=Wih1 2=Whh1
    for (int p = 0; p < 6; ++p) {
        for (int i = tid; i < 3072; i += 512)
            *((uint4*)(smem + UCH_OFF) + i) = F4[(TG1 + p * 48) * 64 + i];
        __syncthreads();
#pragma unroll
        for (int mat = 0; mat < 3; ++mat)
#pragma unroll
            for (int gg = 0; gg < 3; ++gg) {
                int rel0 = mat * 96 + gg * 32 + w * 4;
                if (rel0 >= p * 48 && rel0 < p * 48 + 48) {
#pragma unroll
                    for (int kt = 0; kt < 4; ++kt)
                        wW[mat][gg][kt] = ldsAF(smem + UCH_OFF + (rel0 - p * 48 + kt) * 1024 + lane * 16);
                }
            }
        __syncthreads();
    }

    // ---- per-lane constants & register-resident hold state ----
    const float mb1_c = mb1g[w * 16 + lr];
    const float mbE_l = mbEg[lr];
    float dbc4[4];
#pragma unroll
    for (int i = 0; i < 4; ++i) dbc4[i] = dbCg[lg * 4 + i];
    float hp0[4], hp1[4];
#pragma unroll
    for (int i = 0; i < 4; ++i) {
        hp0[i] = h0g[(r0 + lg * 4 + i) * 128 + w * 16 + lr];
        hp1[i] = h0g[(256 + r0 + lg * 4 + i) * 128 + w * 16 + lr];
    }
    float loss = 0.f;
    const int c2 = (w * 16 + lr) * 2;
    const int bp0 = (lr + (lg & 1) * 32) * 4;  // bpermute byte-addr of x source lane

    for (int t = 0; t < T_STEPS; ++t) {
        const char* h0c = smem + H0_OFF + (t & 1) * 4352;
        char* h0n = smem + H0_OFF + ((t & 1) ^ 1) * 4352;
        const char* h1c = smem + H1_OFF + (t & 1) * 4352;
        char* h1n = smem + H1_OFF + ((t & 1) ^ 1) * 4352;
        const int s = t & 31, sp = (t - 1) & 31;
        const char* h1r = h1c + lr * 272;

        // ======== x(t-1) = [u(t-1)|h1(t-1)] @ dC^T + dbC (redundant per wave, in-register) ====
        bf16x8 ad0 = ldsAF((lg < 2) ? (smem + UCH_OFF + sp * CH_STR + lr * 48 + lg * 16)
                                    : (h1r + (lg - 2) * 16));
        bf16x8 ad1 = ldsAF(h1r + 32 + lg * 16);
        bf16x8 ad2 = ldsAF(h1r + 96 + lg * 16);
        bf16x8 ad3 = ldsAF(h1r + 160 + lg * 16);
        bf16x8 ad4 = ldsAF(h1r + 224 + (lg & 1) * 16);  // lg>=2: K-pad cols, B is zero there
        f32x4 xa = mfma16(ldsAF(smem + WL_OFF + 24 * 1024 + lane * 16), ad0, zero);
        xa = mfma16(ldsAF(smem + WL_OFF + 25 * 1024 + lane * 16), ad1, xa);
        xa = mfma16(ldsAF(smem + WL_OFF + 26 * 1024 + lane * 16), ad2, xa);
        f32x4 xb = mfma16(ldsAF(smem + WL_OFF + 27 * 1024 + lane * 16), ad3, zero);
        xb = mfma16(ldsAF(smem + WL_OFF + 28 * 1024 + lane * 16), ad4, xb);
        uint32 pk0 = cvtpk(xa[0] + xb[0] + dbc4[0], xa[1] + xb[1] + dbc4[1]);
        uint32 pk1 = cvtpk(xa[2] + xb[2] + dbc4[2], xa[3] + xb[3] + dbc4[3]);
        if (t == 0) { pk0 = 0u; pk1 = 0u; }
        uint32 d0 = (uint32)__builtin_amdgcn_ds_bpermute(bp0, (int)pk0);
        uint32 d1 = (uint32)__builtin_amdgcn_ds_bpermute(bp0, (int)pk1);
        uint32 d2 = (uint32)__builtin_amdgcn_ds_bpermute(bp0 + 64, (int)pk0);
        uint32 d3 = (uint32)__builtin_amdgcn_ds_bpermute(bp0 + 64, (int)pk1);
        bf16x8 xfrag = __builtin_bit_cast(bf16x8, (uint4){d0, d1, d2, d3});

        // ---- chunk refill every 32 steps (paired-channel u32 stores, 4-way not 32-way) ----
        if ((t & 31) == 0) {
            __syncthreads();
#pragma unroll
            for (int it = 0; it < 8; ++it) {
                int g = it * 16 + (tid >> 5);     // 0..127 = (rr2, chp)
                int rr2 = g >> 3, chp = g & 7, ss = lane & 31;
                const float* up = u + (r0 + rr2) * 16384 + (2 * chp) * 1024 + t + ss;
                *(uint32*)(smem + UCH_OFF + ss * CH_STR + rr2 * 48 + chp * 4) =
                    cvtpk(up[0], up[1024]);
                int gt = t - 1 + ss;
                const float* yp = yg + (r0 + rr2) * 16384 + (2 * chp) * 1024 + gt;
                uint32 py = (gt >= 0) ? cvtpk(yp[0], yp[1024]) : 0u;
                *(uint32*)(smem + YCH_OFF + ss * CH_STR + rr2 * 48 + chp * 4) = py;
            }
            __syncthreads();
        }

        // ================= PHASE 1: GRU0(t) + m1(t-1) =================
        bf16x8 ufrag = ldsAF(smem + UCH_OFF + s * CH_STR + lr * 48 + (lg & 1) * 16);
        bf16x8 a_inp = (lg < 2) ? ufrag : xfrag;
        const char* h0r = h0c + lr * 272;
        bf16x8 ah0 = ldsAF(h0r + lg * 16);
        bf16x8 ah1 = ldsAF(h0r + 64 + lg * 16);
        bf16x8 ah2 = ldsAF(h0r + 128 + lg * 16);
        bf16x8 ah3 = ldsAF(h0r + 192 + lg * 16);
        bf16x8 b0r = ldsAF(smem + WL_OFF + (0 * 8 + w) * 1024 + lane * 16);
        bf16x8 b0z = ldsAF(smem + WL_OFF + (1 * 8 + w) * 1024 + lane * 16);
        bf16x8 b0n = ldsAF(smem + WL_OFF + (2 * 8 + w) * 1024 + lane * 16);
        f32x4 rA = mfma16(ah0, wW[0][0][0], zero);
        rA = mfma16(ah1, wW[0][0][1], rA);
        rA = mfma16(a_inp, b0r, rA);
        f32x4 rB = mfma16(ah2, wW[0][0][2], zero);
        rB = mfma16(ah3, wW[0][0][3], rB);
        f32x4 zA = mfma16(ah0, wW[0][1][0], zero);
        zA = mfma16(ah1, wW[0][1][1], zA);
        zA = mfma16(a_inp, b0z, zA);
        f32x4 zB = mfma16(ah2, wW[0][1][2], zero);
        zB = mfma16(ah3, wW[0][1][3], zB);
        f32x4 nI = mfma16(a_inp, b0n, zero);
        f32x4 nA = mfma16(ah0, wW[0][2][0], zero);
        nA = mfma16(ah1, wW[0][2][1], nA);
        f32x4 nB = mfma16(ah2, wW[0][2][2], zero);
        nB = mfma16(ah3, wW[0][2][3], nB);
        // m1(t-1) = relu([x(t-1), h0(t-1)] @ mW1^T + mb1)
        bf16x8 am0 = (lg < 2) ? xfrag : ldsAF(h0r + (lg - 2) * 16);
        bf16x8 am1 = ldsAF(h0r + 32 + lg * 16);
        bf16x8 am2 = ldsAF(h0r + 96 + lg * 16);
        bf16x8 am3 = ldsAF(h0r + 160 + lg * 16);
        bf16x8 am4 = ldsAF(h0r + 224 + (lg & 1) * 16);  // K-pad cols: B zero
        const int mb = 29 + w * 5;
        f32x4 mA = mfma16(am1, ldsAF(smem + WL_OFF + (mb + 1) * 1024 + lane * 16), zero);
        mA = mfma16(am2, ldsAF(smem + WL_OFF + (mb + 2) * 1024 + lane * 16), mA);
        mA = mfma16(am0, ldsAF(smem + WL_OFF + (mb + 0) * 1024 + lane * 16), mA);
        f32x4 mB = mfma16(am3, ldsAF(smem + WL_OFF + (mb + 3) * 1024 + lane * 16), zero);
        mB = mfma16(am4, ldsAF(smem + WL_OFF + (mb + 4) * 1024 + lane * 16), mB);
#pragma unroll
        for (int i = 0; i < 4; ++i) {
            float rr = sigm(rA[i] + rB[i]);
            float zz = sigm(zA[i] + zB[i]);
            float nn = tanh_fast(fmaf(rr, nA[i] + nB[i], nI[i]));
            float hnew = fmaf(zz, hp0[i] - nn, nn);
            hp0[i] = hnew;
            *(u16*)(h0n + (lg * 4 + i) * 272 + c2) = (u16)cvtpk(hnew, hnew);
            float mv = fmaxf(mA[i] + mB[i] + mb1_c, 0.f);
            *(u16*)(smem + M1_OFF + (lg * 4 + i) * 272 + c2) = (u16)cvtpk(mv, mv);
        }
        __syncthreads();

        // ================= PHASE 2: GRU1(t) + loss(t-1) =================
        const char* h0nr = h0n + lr * 272;
        bf16x8 ag0 = ldsAF(h0nr + lg * 16);
        bf16x8 ag1 = ldsAF(h0nr + 64 + lg * 16);
        bf16x8 ag2 = ldsAF(h0nr + 128 + lg * 16);
        bf16x8 ag3 = ldsAF(h0nr + 192 + lg * 16);
        bf16x8 av0 = ldsAF(h1r + lg * 16);
        bf16x8 av1 = ldsAF(h1r + 64 + lg * 16);
        bf16x8 av2 = ldsAF(h1r + 128 + lg * 16);
        bf16x8 av3 = ldsAF(h1r + 192 + lg * 16);
        bf16x8 q0, q1, q2, q3, we0, we1, we2, we3;
        if (w == 7) {
            const char* m1r = smem + M1_OFF + lr * 272;
            q0 = ldsAF(m1r + lg * 16);
            q1 = ldsAF(m1r + 64 + lg * 16);
            q2 = ldsAF(m1r + 128 + lg * 16);
            q3 = ldsAF(m1r + 192 + lg * 16);
            we0 = ldsAF(smem + WL_OFF + 69 * 1024 + lane * 16);
            we1 = ldsAF(smem + WL_OFF + 70 * 1024 + lane * 16);
            we2 = ldsAF(smem + WL_OFF + 71 * 1024 + lane * 16);
            we3 = ldsAF(smem + WL_OFF + 72 * 1024 + lane * 16);
        }
        f32x4 bRi = mfma16(ag0, wW[1][0][0], zero);
        bRi = mfma16(ag1, wW[1][0][1], bRi);
        bRi = mfma16(ag2, wW[1][0][2], bRi);
        bRi = mfma16(ag3, wW[1][0][3], bRi);
        f32x4 bRh = mfma16(av0, wW[2][0][0], zero);
        bRh = mfma16(av1, wW[2][0][1], bRh);
        bRh = mfma16(av2, wW[2][0][2], bRh);
        bRh = mfma16(av3, wW[2][0][3], bRh);
        f32x4 bZi = mfma16(ag0, wW[1][1][0], zero);
        bZi = mfma16(ag1, wW[1][1][1], bZi);
        bZi = mfma16(ag2, wW[1][1][2], bZi);
        bZi = mfma16(ag3, wW[1][1][3], bZi);
        f32x4 bZh = mfma16(av0, wW[2][1][0], zero);
        bZh = mfma16(av1, wW[2][1][1], bZh);
        bZh = mfma16(av2, wW[2][1][2], bZh);
        bZh = mfma16(av3, wW[2][1][3], bZh);
        f32x4 bNi = mfma16(ag0, wW[1][2][0], zero);
        bNi = mfma16(ag1, wW[1][2][1], bNi);
        bNi = mfma16(ag2, wW[1][2][2], bNi);
        bNi = mfma16(ag3, wW[1][2][3], bNi);
        f32x4 bNh = mfma16(av0, wW[2][2][0], zero);
        bNh = mfma16(av1, wW[2][2][1], bNh);
        bNh = mfma16(av2, wW[2][2][2], bNh);
        bNh = mfma16(av3, wW[2][2][3], bNh);
        if (w == 7) {  // y_hat(t-1) = m1(t-1) @ mE^T + mbE ; loss
            f32x4 lA = mfma16(q0, we0, zero);
            lA = mfma16(q1, we1, lA);
            f32x4 lB = mfma16(q2, we2, zero);
            lB = mfma16(q3, we3, lB);
            const float gd = (t > 0) ? 1.f : 0.f;
#pragma unroll
            for (int i = 0; i < 4; ++i) {
                float yh = lA[i] + lB[i] + mbE_l;
                float yv = bf2f(*(const u16*)(smem + YCH_OFF + s * CH_STR + (lg * 4 + i) * 48 + lr * 2));
                float d = yh - yv;
                loss = fmaf(gd * d, d, loss);
            }
        }
#pragma unroll
        for (int i = 0; i < 4; ++i) {
            float rr = sigm(bRi[i] + bRh[i]);
            float zz = sigm(bZi[i] + bZh[i]);
            float nn = tanh_fast(fmaf(rr, bNh[i], bNi[i]));
            float hnew = fmaf(zz, hp1[i] - nn, nn);
            hp1[i] = hnew;
            *(u16*)(h1n + (lg * 4 + i) * 272 + c2) = (u16)cvtpk(hnew, hnew);
        }
        __syncthreads();
    }

    // ================= tail: m1(1023) + loss(1023) =================
    {
        const char* h0c = smem + H0_OFF;   // buffer 0 = h0n(1023)
        const char* h1c = smem + H1_OFF;   // buffer 0 = h1n(1023)
        const char* h1r = h1c + lr * 272;
        const char* h0r = h0c + lr * 272;
        bf16x8 ad0 = ldsAF((lg < 2) ? (smem + UCH_OFF + 31 * CH_STR + lr * 48 + lg * 16)
                                    : (h1r + (lg - 2) * 16));
        bf16x8 ad1 = ldsAF(h1r + 32 + lg * 16);
        bf16x8 ad2 = ldsAF(h1r + 96 + lg * 16);
        bf16x8 ad3 = ldsAF(h1r + 160 + lg * 16);
        bf16x8 ad4 = ldsAF(h1r + 224 + (lg & 1) * 16);
        f32x4 xa = mfma16(ldsAF(smem + WL_OFF + 24 * 1024 + lane * 16), ad0, zero);
        xa = mfma16(ldsAF(smem + WL_OFF + 25 * 1024 + lane * 16), ad1, xa);
        xa = mfma16(ldsAF(smem + WL_OFF + 26 * 1024 + lane * 16), ad2, xa);
        f32x4 xb = mfma16(ldsAF(smem + WL_OFF + 27 * 1024 + lane * 16), ad3, zero);
        xb = mfma16(ldsAF(smem + WL_OFF + 28 * 1024 + lane * 16), ad4, xb);
        uint32 pk0 = cvtpk(xa[0] + xb[0] + dbc4[0], xa[1] + xb[1] + dbc4[1]);
        uint32 pk1 = cvtpk(xa[2] + xb[2] + dbc4[2], xa[3] + xb[3] + dbc4[3]);
        uint32 d0 = (uint32)__builtin_amdgcn_ds_bpermute(bp0, (int)pk0);
        uint32 d1 = (uint32)__builtin_amdgcn_ds_bpermute(bp0, (int)pk1);
        uint32 d2 = (uint32)__builtin_amdgcn_ds_bpermute(bp0 + 64, (int)pk0);
        uint32 d3 = (uint32)__builtin_amdgcn_ds_bpermute(bp0 + 64, (int)pk1);
        bf16x8 xfrag = __builtin_bit_cast(bf16x8, (uint4){d0, d1, d2, d3});
        bf16x8 am0 = (lg < 2) ? xfrag : ldsAF(h0r + (lg - 2) * 16);
        bf16x8 am1 = ldsAF(h0r + 32 + lg * 16);
        bf16x8 am2 = ldsAF(h0r + 96 + lg * 16);
        bf16x8 am3 = ldsAF(h0r + 160 + lg * 16);
        bf16x8 am4 = ldsAF(h0r + 224 + (lg & 1) * 16);
        const int mb = 29 + w * 5;
        f32x4 m = mfma16(am0, ldsAF(smem + WL_OFF + (mb + 0) * 1024 + lane * 16), zero);
        m = mfma16(am1, ldsAF(smem + WL_OFF + (mb + 1) * 1024 + lane * 16), m);
        m = mfma16(am2, ldsAF(smem + WL_OFF + (mb + 2) * 1024 + lane * 16), m);
        m = mfma16(am3, ldsAF(smem + WL_OFF + (mb + 3) * 1024 + lane * 16), m);
        m = mfma16(am4, ldsAF(smem + WL_OFF + (mb + 4) * 1024 + lane * 16), m);
#pragma unroll
        for (int i = 0; i < 4; ++i) {
            float mv = fmaxf(m[i] + mb1_c, 0.f);
            *(u16*)(smem + M1_OFF + (lg * 4 + i) * 272 + c2) = (u16)cvtpk(mv, mv);
        }
        __syncthreads();
        if (w == 7) {
            const char* m1r = smem + M1_OFF + lr * 272;
            bf16x8 q0 = ldsAF(m1r + lg * 16);
            bf16x8 q1 = ldsAF(m1r + 64 + lg * 16);
            bf16x8 q2 = ldsAF(m1r + 128 + lg * 16);
            bf16x8 q3 = ldsAF(m1r + 192 + lg * 16);
            f32x4 lA = mfma16(q0, ldsAF(smem + WL_OFF + 69 * 1024 + lane * 16), zero);
            lA = mfma16(q1, ldsAF(smem + WL_OFF + 70 * 1024 + lane * 16), lA);
            f32x4 lB = mfma16(q2, ldsAF(smem + WL_OFF + 71 * 1024 + lane * 16), zero);
            lB = mfma16(q3, ldsAF(smem + WL_OFF + 72 * 1024 + lane * 16), lB);
#pragma unroll
            for (int i = 0; i < 4; ++i) {
                float yh = lA[i] + lB[i] + mbE_l;
                float yv = yg[(r0 + lg * 4 + i) * 16384 + lr * 1024 + 1023];
                float d = yh - yv;
                loss = fmaf(d, d, loss);
            }
        }
    }

    if (w == 7) {
#pragma unroll
        for (int off = 32; off > 0; off >>= 1) loss += __shfl_down(loss, off, 64);
        if (lane == 0) atomicAdd(out, loss);
    }
}

extern "C" void kernel_launch(void* const* d_in, const int* in_sizes, int n_in,
                              void* d_out, int out_size, void* d_ws, size_t ws_size,
                              hipStream_t stream) {
    const float* u    = (const float*)d_in[0];
    const float* y    = (const float*)d_in[1];
    const float* h0   = (const float*)d_in[2];
    const float* Wih0 = (const float*)d_in[3];
    const float* Whh0 = (const float*)d_in[4];
    const float* Wih1 = (const float*)d_in[5];
    const float* Whh1 = (const float*)d_in[6];
    const float* dW1  = (const float*)d_in[7];
    const float* db1  = (const float*)d_in[8];
    const float* dW2  = (const float*)d_in[9];
    const float* db2  = (const float*)d_in[10];
    const float* mW1  = (const float*)d_in[11];
    const float* mb1  = (const float*)d_in[12];
    const float* mW2  = (const float*)d_in[13];
    const float* mb2  = (const float*)d_in[14];
    const float* mW3  = (const float*)d_in[15];
    const float* mb3  = (const float*)d_in[16];
    float* out = (float*)d_out;
    char* ws = (char*)d_ws;

    prep1<<<dim3(18), dim3(256), 0, stream>>>(dW1, db1, dW2, db2, mW2, mb2, mW3, mb3, ws, out);
    prep2<<<dim3(NT_TOT), dim3(64), 0, stream>>>(Wih0, Whh0, Wih1, Whh1, mW1, ws);
    rnn_main<<<dim3(16), dim3(512), 0, stream>>>(u, y, h0, ws, mb1,
                                                 (const float*)(ws + SC_DBC),
                                                 (const float*)(ws + SC_MBE), out);
}